// Round 1
// baseline (345.932 us; speedup 1.0000x reference)
//
#include <hip/hip_runtime.h>
#include <cmath>

// Problem constants (fixed by reference)
#define SS 3
#define NN 8192
#define EE 1024
#define DD 512
#define ALPHA 3.0f

// GEMM tiling
#define BM 128
#define BN 128
#define BK 16
#define TM 8
#define TN 8
// 256 threads = (BM/TM) * (BN/TN) = 16 * 16

// Kernel 1: sim = node @ edge^T per scale, fused z = relu(alpha * sim),
// written to out (used as scratch; kernel 2 overwrites with binary).
__global__ __launch_bounds__(256, 2)
void gemm_relu_kernel(const float* __restrict__ node,
                      const float* __restrict__ edge,
                      float* __restrict__ out)
{
    const int s  = blockIdx.z;
    const int m0 = blockIdx.y * BM;
    const int n0 = blockIdx.x * BN;

    const float* A = node + (size_t)s * NN * DD;  // [NN][DD]
    const float* B = edge + (size_t)s * EE * DD;  // [EE][DD]
    float*       C = out  + (size_t)s * NN * EE;  // [NN][EE]

    __shared__ float As[BK][BM + 4];
    __shared__ float Bs[BK][BN + 4];

    const int tid = threadIdx.x;
    const int tx  = tid % 16;   // col group (n)
    const int ty  = tid / 16;   // row group (m)

    // staging: each thread loads 2 float4 from A tile + 2 from B tile
    const int lrow = tid / 4;        // 0..63
    const int lcol = (tid % 4) * 4;  // 0,4,8,12

    float acc[TM][TN];
#pragma unroll
    for (int i = 0; i < TM; ++i)
#pragma unroll
        for (int j = 0; j < TN; ++j) acc[i][j] = 0.f;

    for (int k0 = 0; k0 < DD; k0 += BK) {
#pragma unroll
        for (int p = 0; p < 2; ++p) {
            const int r = lrow + p * 64;
            float4 v = *(const float4*)(A + (size_t)(m0 + r) * DD + k0 + lcol);
            As[lcol + 0][r] = v.x;
            As[lcol + 1][r] = v.y;
            As[lcol + 2][r] = v.z;
            As[lcol + 3][r] = v.w;
            float4 w = *(const float4*)(B + (size_t)(n0 + r) * DD + k0 + lcol);
            Bs[lcol + 0][r] = w.x;
            Bs[lcol + 1][r] = w.y;
            Bs[lcol + 2][r] = w.z;
            Bs[lcol + 3][r] = w.w;
        }
        __syncthreads();

#pragma unroll
        for (int k = 0; k < BK; ++k) {
            float a[TM], b[TN];
            float4 a0 = *(const float4*)&As[k][ty * 8];
            float4 a1 = *(const float4*)&As[k][ty * 8 + 4];
            a[0]=a0.x; a[1]=a0.y; a[2]=a0.z; a[3]=a0.w;
            a[4]=a1.x; a[5]=a1.y; a[6]=a1.z; a[7]=a1.w;
            float4 b0 = *(const float4*)&Bs[k][tx * 8];
            float4 b1 = *(const float4*)&Bs[k][tx * 8 + 4];
            b[0]=b0.x; b[1]=b0.y; b[2]=b0.z; b[3]=b0.w;
            b[4]=b1.x; b[5]=b1.y; b[6]=b1.z; b[7]=b1.w;
#pragma unroll
            for (int i = 0; i < TM; ++i)
#pragma unroll
                for (int j = 0; j < TN; ++j)
                    acc[i][j] = fmaf(a[i], b[j], acc[i][j]);
        }
        __syncthreads();
    }

    // epilogue: z = relu(alpha * acc)
#pragma unroll
    for (int i = 0; i < TM; ++i) {
        const size_t row = (size_t)(m0 + ty * 8 + i);
        float4 o0, o1;
        o0.x = fmaxf(ALPHA * acc[i][0], 0.f);
        o0.y = fmaxf(ALPHA * acc[i][1], 0.f);
        o0.z = fmaxf(ALPHA * acc[i][2], 0.f);
        o0.w = fmaxf(ALPHA * acc[i][3], 0.f);
        o1.x = fmaxf(ALPHA * acc[i][4], 0.f);
        o1.y = fmaxf(ALPHA * acc[i][5], 0.f);
        o1.z = fmaxf(ALPHA * acc[i][6], 0.f);
        o1.w = fmaxf(ALPHA * acc[i][7], 0.f);
        *(float4*)(C + row * EE + n0 + tx * 8)     = o0;
        *(float4*)(C + row * EE + n0 + tx * 8 + 4) = o1;
    }
}

// Kernel 2: per row of 1024 z-values (already relu(alpha*sim)):
// out[e] = (exp(z_e - m) > 0.5 * sum_e' exp(z_e' - m)) ? 1 : 0
// One wave (64 lanes) per row, 16 elements per lane, in-place.
__global__ __launch_bounds__(256)
void softmax_threshold_kernel(float* __restrict__ out)
{
    const int wave = threadIdx.x >> 6;
    const int lane = threadIdx.x & 63;
    const size_t row = (size_t)blockIdx.x * 4 + wave;  // SS*NN rows total
    float* p = out + row * EE;

    float z[16];
    float m = 0.f;  // z >= 0 always (relu output)
#pragma unroll
    for (int j = 0; j < 4; ++j) {
        float4 v = *(const float4*)(p + j * 256 + lane * 4);
        z[j*4+0] = v.x; z[j*4+1] = v.y; z[j*4+2] = v.z; z[j*4+3] = v.w;
        m = fmaxf(m, fmaxf(fmaxf(v.x, v.y), fmaxf(v.z, v.w)));
    }
    // wave-wide max reduce
#pragma unroll
    for (int off = 32; off >= 1; off >>= 1)
        m = fmaxf(m, __shfl_xor(m, off, 64));

    float e[16];
    float sum = 0.f;
#pragma unroll
    for (int j = 0; j < 16; ++j) {
        e[j] = expf(z[j] - m);
        sum += e[j];
    }
#pragma unroll
    for (int off = 32; off >= 1; off >>= 1)
        sum += __shfl_xor(sum, off, 64);

    const float thr = 0.5f * sum;
#pragma unroll
    for (int j = 0; j < 4; ++j) {
        float4 o;
        o.x = (e[j*4+0] > thr) ? 1.f : 0.f;
        o.y = (e[j*4+1] > thr) ? 1.f : 0.f;
        o.z = (e[j*4+2] > thr) ? 1.f : 0.f;
        o.w = (e[j*4+3] > thr) ? 1.f : 0.f;
        *(float4*)(p + j * 256 + lane * 4) = o;
    }
}

extern "C" void kernel_launch(void* const* d_in, const int* in_sizes, int n_in,
                              void* d_out, int out_size, void* d_ws, size_t ws_size,
                              hipStream_t stream) {
    const float* node = (const float*)d_in[1];  // [S, N, D]
    const float* edge = (const float*)d_in[2];  // [S, E, D]
    float* out = (float*)d_out;                 // [S, N, E]

    dim3 g1(EE / BN, NN / BM, SS);  // 8 x 64 x 3 = 1536 blocks
    gemm_relu_kernel<<<g1, 256, 0, stream>>>(node, edge, out);

    softmax_threshold_kernel<<<(SS * NN) / 4, 256, 0, stream>>>(out);
}